// Round 4
// baseline (2641.166 us; speedup 1.0000x reference)
//
#include <hip/hip_runtime.h>

// Decoder_48378511622552 — CSR-sorted, bf16/f32, K=128 MFMA fused GNN decoder (gfx950)
// Round 4: cvt_pk bf16, fast elu, f32 addend tables, fused LIN3, direct u16 stores.

#define HD   128
#define NC   50000
#define NF   150000
#define ECNT 400000
#define OUTD 3
#define SCB  512
#define NB_SCAN ((NF + SCB - 1) / SCB)   // 293

typedef unsigned short u16;
typedef unsigned int   u32;
typedef short bf16x8 __attribute__((ext_vector_type(8)));
typedef float f32x4  __attribute__((ext_vector_type(4)));

__device__ __forceinline__ float bf2f(u32 u){ return __uint_as_float(u << 16); }
__device__ __forceinline__ u32 cvtpk(float a, float b){   // lo = bf16(a), hi = bf16(b)
  u32 r; asm("v_cvt_pk_bf16_f32 %0, %1, %2" : "=v"(r) : "v"(a), "v"(b)); return r;
}
__device__ __forceinline__ u16 f2bf(float f){ return (u16)cvtpk(f, f); }
__device__ __forceinline__ float eluf(float x){ return x > 0.f ? x : __expf(x) - 1.f; }
// swizzles: SW for bf16 [32][256B] tiles, SWF for f32 [32][512B] tiles
__device__ __forceinline__ int SW (int row, int byte){ return row * 256 + (byte ^ ((row & 7) << 4)); }
__device__ __forceinline__ int SWF(int row, int byte){ return row * 512 + (byte ^ (((row >> 2) & 1) << 6)); }

// ---------------- prep kernels ----------------

// chunked bf16 weights: out[((k>>3)*128 + j)*8 + (k&7)] = bf16(W[k*128 + j])
__global__ void prep_w_kernel(const float* __restrict__ W, u16* __restrict__ out, int K){
  int idx = blockIdx.x * blockDim.x + threadIdx.x;
  if (idx >= K * HD) return;
  int k = idx / HD, j = idx % HD;
  out[(((k >> 3) * HD + j) << 3) + (k & 7)] = f2bf(W[k * HD + j]);
}

__global__ void f32_to_bf16_vec(const float* __restrict__ in, u16* __restrict__ out, int n8){
  int i = blockIdx.x * blockDim.x + threadIdx.x;
  if (i >= n8) return;
  float4 f0 = ((const float4*)in)[i * 2];
  float4 f1 = ((const float4*)in)[i * 2 + 1];
  ((uint4*)out)[i] = make_uint4(cvtpk(f0.x,f0.y), cvtpk(f0.z,f0.w), cvtpk(f1.x,f1.y), cvtpk(f1.z,f1.w));
}

__global__ void deg_kernel(const int* __restrict__ ei, int* __restrict__ deg){
  int e = blockIdx.x * blockDim.x + threadIdx.x;
  if (e < ECNT) atomicAdd(&deg[ei[ECNT + e]], 1);
}

__global__ void scanA_kernel(const int* __restrict__ deg, int* __restrict__ part){
  __shared__ int s[SCB];
  int t = threadIdx.x, i = blockIdx.x * SCB + t;
  s[t] = (i < NF) ? deg[i] : 0;
  __syncthreads();
  for (int off = SCB/2; off; off >>= 1){ if (t < off) s[t] += s[t + off]; __syncthreads(); }
  if (t == 0) part[blockIdx.x] = s[0];
}

__global__ void scanB_kernel(int* __restrict__ part){
  __shared__ int s[SCB];
  int t = threadIdx.x;
  int v = (t < NB_SCAN) ? part[t] : 0;
  s[t] = v; __syncthreads();
  for (int off = 1; off < SCB; off <<= 1){
    int x = (t >= off) ? s[t - off] : 0;
    __syncthreads(); s[t] += x; __syncthreads();
  }
  if (t < NB_SCAN) part[t] = s[t] - v;   // exclusive
}

__global__ void scanC_kernel(const int* __restrict__ deg, const int* __restrict__ part,
                             int* __restrict__ rowptr){
  __shared__ int s[SCB];
  int t = threadIdx.x, i = blockIdx.x * SCB + t;
  int v = (i < NF) ? deg[i] : 0;
  s[t] = v; __syncthreads();
  for (int off = 1; off < SCB; off <<= 1){
    int x = (t >= off) ? s[t - off] : 0;
    __syncthreads(); s[t] += x; __syncthreads();
  }
  int excl = part[blockIdx.x] + s[t] - v;
  if (i < NF) rowptr[i] = excl;
  if (i == NF - 1) rowptr[NF] = excl + v;
}

__global__ void build_perm_kernel(const int* __restrict__ ei, int* __restrict__ cursor,
                                  int* __restrict__ perm, int* __restrict__ esrc,
                                  int* __restrict__ edst){
  int e = blockIdx.x * blockDim.x + threadIdx.x;
  if (e >= ECNT) return;
  int sI = ei[e], d = ei[ECNT + e];
  int p = atomicAdd(&cursor[d], 1);
  perm[p] = e; esrc[p] = sI; edst[p] = d;
}

__global__ void permute_ea_kernel(const float* __restrict__ ea_in, const int* __restrict__ perm,
                                  u16* __restrict__ ea_s){
  int i = blockIdx.x * blockDim.x + threadIdx.x;
  if (i >= ECNT * 16) return;
  int p = i >> 4, c = i & 15;
  int e = perm[p];
  const float4* src = (const float4*)(ea_in + (size_t)e * HD + c * 8);
  float4 f0 = src[0], f1 = src[1];
  ((uint4*)ea_s)[(size_t)p * 16 + c] =
      make_uint4(cvtpk(f0.x,f0.y), cvtpk(f0.z,f0.w), cvtpk(f1.x,f1.y), cvtpk(f1.z,f1.w));
}

// ---------------- fused LIN (1 or 3 outputs): o[w] = x @ W[w], f32 out ----------------
template<int NOUT>
__global__ __launch_bounds__(256, 4)
void lin_kernel(const u16* __restrict__ Wa, const u16* __restrict__ Wb, const u16* __restrict__ Wc,
                const u16* __restrict__ x, float* __restrict__ oA, float* __restrict__ oB,
                float* __restrict__ oC, int n_rows)
{
  __shared__ __align__(16) char ldsA[32 * 256];
  const int tid = threadIdx.x, lane = tid & 63, wid = tid >> 6;
  const int ln = lane & 15, kq = lane >> 4, ncol = wid * 32;
  const int tiles = (n_rows + 31) >> 5;

  for (int tile = blockIdx.x; tile < tiles; tile += gridDim.x){
    const int row0 = tile << 5;
    #pragma unroll
    for (int c = 0; c < 2; ++c){
      int i = tid + c * 256, row = i >> 4, kk = i & 15, rg = row0 + row;
      if (rg < n_rows)
        *(uint4*)(ldsA + SW(row, kk * 16)) = *(const uint4*)(x + (((size_t)rg) << 7) + (kk << 3));
    }
    __syncthreads();
    bf16x8 af[4][2];
    #pragma unroll
    for (int k0 = 0; k0 < 4; ++k0){
      af[k0][0] = *(const bf16x8*)(ldsA + SW(ln,      k0 * 64 + (kq << 4)));
      af[k0][1] = *(const bf16x8*)(ldsA + SW(16 + ln, k0 * 64 + (kq << 4)));
    }
    __syncthreads();   // all frag reads done -> next stage may overwrite

    const u16* Ws[3] = {Wa, Wb, Wc};
    float*     Os[3] = {oA, oB, oC};
    const f32x4 zz = {0.f, 0.f, 0.f, 0.f};
    #pragma unroll
    for (int w = 0; w < NOUT; ++w){
      const u16* wp = Ws[w];
      asm volatile("" : "+v"(wp));   // anti-hoist: keep b-frags transient per tile
      uint4 bf[4][2];
      #pragma unroll
      for (int k0 = 0; k0 < 4; ++k0)
        #pragma unroll
        for (int nt = 0; nt < 2; ++nt)
          bf[k0][nt] = *(const uint4*)(wp + (((size_t)((k0*4 + kq)*HD + ncol + nt*16 + ln)) << 3));
      f32x4 cc[2][2] = {{zz, zz}, {zz, zz}};
      #pragma unroll
      for (int k0 = 0; k0 < 4; ++k0){
        bf16x8 w0 = __builtin_bit_cast(bf16x8, bf[k0][0]);
        bf16x8 w1 = __builtin_bit_cast(bf16x8, bf[k0][1]);
        cc[0][0] = __builtin_amdgcn_mfma_f32_16x16x32_bf16(af[k0][0], w0, cc[0][0], 0, 0, 0);
        cc[0][1] = __builtin_amdgcn_mfma_f32_16x16x32_bf16(af[k0][0], w1, cc[0][1], 0, 0, 0);
        cc[1][0] = __builtin_amdgcn_mfma_f32_16x16x32_bf16(af[k0][1], w0, cc[1][0], 0, 0, 0);
        cc[1][1] = __builtin_amdgcn_mfma_f32_16x16x32_bf16(af[k0][1], w1, cc[1][1], 0, 0, 0);
      }
      float* op = Os[w];
      #pragma unroll
      for (int mi = 0; mi < 2; ++mi)
        #pragma unroll
        for (int nt = 0; nt < 2; ++nt)
          #pragma unroll
          for (int r = 0; r < 4; ++r){
            int rg = row0 + mi * 16 + kq * 4 + r;
            if (rg < n_rows) op[(size_t)rg * HD + ncol + nt * 16 + ln] = cc[mi][nt][r];
          }
    }
  }
}

// ---------------- unified fused K=128 MFMA MLP ----------------
enum { M_DEC1 = 0, M_EDGE = 1, M_NODE = 2, M_DEC2 = 3 };

// EDGE: A = ea;  h = elu(A@W0 + P[src]+Q[dst] + b0); o = h@W1 + b1;        out = LN(resid + o)
// NODE: A = CSR-mean(ea); h = elu(A@W0 + T[row] + b0); o = h@W1 + b1;     out = LN(resid + o)
// DEC2: A = eac; h = elu(A@W0 + XU[clus] + b0); o = elu(h@W1 + b1);       out = LN(resid + o)
// DEC1: A = elu(delta@dW0+db0) inline; out = elu(A@W0 + b0)
template<int MODE>
__global__ __launch_bounds__(256, 4)
void mlp_kernel(const u16* __restrict__ W0c, const u16* __restrict__ W1c,
                const float* __restrict__ b0, const float* __restrict__ b1,
                const float* __restrict__ gw, const float* __restrict__ bw,
                const u16* __restrict__ tabA, const float* __restrict__ addP,
                const float* __restrict__ addQ, const u16* __restrict__ resid,
                const int* __restrict__ esrc, const int* __restrict__ edst,
                const int* __restrict__ rowptr, const u16* __restrict__ eatab,
                const int* __restrict__ clus,
                u16* __restrict__ outp, int n_rows,
                const float* __restrict__ dW0, const float* __restrict__ db0,
                const float* __restrict__ pos_c, const float* __restrict__ pos_f)
{
  constexpr bool HAS2 = (MODE != M_DEC1);
  constexpr bool ELU2 = (MODE == M_DEC2);

  __shared__ __align__(16) char  ldsA [32 * 256];          // bf16 A tile
  __shared__ __align__(16) float ldsPQ[32 * 128];          // f32 addend / r staging
  __shared__ __align__(16) char  ldsH [HAS2 ? 32 * 256 : 16];

  const int tid  = threadIdx.x;
  const int lane = tid & 63;
  const int wid  = tid >> 6;          // 0..3
  const int ln   = lane & 15, kq = lane >> 4;
  const int ncol = wid * 32;

  bf16x8 b1f[4][2];
  #pragma unroll
  for (int k0 = 0; k0 < 4; ++k0)
    #pragma unroll
    for (int nt = 0; nt < 2; ++nt)
      b1f[k0][nt] = *(const bf16x8*)(W0c + (((size_t)((k0*4 + kq)*HD + ncol + nt*16 + ln)) << 3));

  float b0v[2], b1v[2] = {0.f, 0.f};
  #pragma unroll
  for (int nt = 0; nt < 2; ++nt) b0v[nt] = b0[ncol + nt*16 + ln];
  float gl0 = 0.f, gl1 = 0.f, bt0 = 0.f, bt1 = 0.f;
  if constexpr (HAS2){
    #pragma unroll
    for (int nt = 0; nt < 2; ++nt) b1v[nt] = b1[ncol + nt*16 + ln];
    gl0 = gw[lane]; gl1 = gw[64 + lane]; bt0 = bw[lane]; bt1 = bw[64 + lane];
  }

  const int tiles = (n_rows + 31) >> 5;

  for (int tile = blockIdx.x; tile < tiles; tile += gridDim.x){
    const int row0 = tile << 5;

    // ---------------- stage ----------------
    if constexpr (MODE == M_EDGE){
      #pragma unroll
      for (int c = 0; c < 2; ++c){           // ea tile (ECNT % 32 == 0: no guard)
        int i = tid + c * 256, row = i >> 4, kk = i & 15, rg = row0 + row;
        *(uint4*)(ldsA + SW(row, kk * 16)) =
            *(const uint4*)(tabA + (((size_t)rg) << 7) + (kk << 3));
      }
      #pragma unroll
      for (int c = 0; c < 4; ++c){           // P[src] + Q[dst], f32
        int i = tid + c * 256, row = i >> 5, ch = i & 31, rg = row0 + row;
        int sI = esrc[rg], dI = edst[rg];
        float4 p = *(const float4*)(addP + (((size_t)sI) << 7) + (ch << 2));
        float4 q = *(const float4*)(addQ + (((size_t)dI) << 7) + (ch << 2));
        p.x += q.x; p.y += q.y; p.z += q.z; p.w += q.w;
        *(float4*)((char*)ldsPQ + SWF(row, ch * 16)) = p;
      }
    } else if constexpr (MODE == M_DEC2){
      #pragma unroll
      for (int c = 0; c < 2; ++c){
        int i = tid + c * 256, row = i >> 4, kk = i & 15, rg = row0 + row;
        if (rg < n_rows)
          *(uint4*)(ldsA + SW(row, kk * 16)) =
              *(const uint4*)(tabA + (((size_t)rg) << 7) + (kk << 3));
      }
      #pragma unroll
      for (int c = 0; c < 4; ++c){
        int i = tid + c * 256, row = i >> 5, ch = i & 31, rg = row0 + row;
        if (rg < n_rows){
          int cl = clus[rg];
          *(float4*)((char*)ldsPQ + SWF(row, ch * 16)) =
              *(const float4*)(addP + (((size_t)cl) << 7) + (ch << 2));
        }
      }
    } else if constexpr (MODE == M_NODE){
      #pragma unroll
      for (int c = 0; c < 4; ++c){           // T[row], f32
        int i = tid + c * 256, row = i >> 5, ch = i & 31, rg = row0 + row;
        if (rg < n_rows)
          *(float4*)((char*)ldsPQ + SWF(row, ch * 16)) =
              *(const float4*)(addP + (((size_t)rg) << 7) + (ch << 2));
      }
      // CSR mean of ea -> ldsA; wave handles 8 nodes, lane covers cols (2*lane, 2*lane+1)
      for (int s = 0; s < 8; ++s){
        int nd = wid * 8 + s, rg = row0 + nd;
        if (rg < n_rows){
          int rp0 = rowptr[rg], rp1 = rowptr[rg + 1];
          float s0 = 0.f, s1 = 0.f;
          int i2 = rp0;
          for (; i2 + 1 < rp1; i2 += 2){
            u32 ua = *(const u32*)(eatab + (((size_t)i2) << 7) + (lane << 1));
            u32 ub = *(const u32*)(eatab + (((size_t)(i2+1)) << 7) + (lane << 1));
            s0 += bf2f(ua & 0xffffu) + bf2f(ub & 0xffffu);
            s1 += bf2f(ua >> 16)     + bf2f(ub >> 16);
          }
          if (i2 < rp1){
            u32 ua = *(const u32*)(eatab + (((size_t)i2) << 7) + (lane << 1));
            s0 += bf2f(ua & 0xffffu); s1 += bf2f(ua >> 16);
          }
          int dg = rp1 - rp0;
          float rd = 1.f / (float)(dg > 0 ? dg : 1);
          *(u32*)(ldsA + SW(nd, lane << 2)) = cvtpk(s0 * rd, s1 * rd);
        }
      }
    } else { // M_DEC1: inline h1 = elu(delta @ dW0 + db0) -> ldsA
      #pragma unroll
      for (int c = 0; c < 2; ++c){
        int i = tid + c * 256, row = i >> 4, c8 = i & 15, rg = row0 + row;
        if (rg < n_rows){
          int cl = clus[rg];
          float d0 = pos_c[cl * 2]     - pos_f[rg * 2];
          float d1 = pos_c[cl * 2 + 1] - pos_f[rg * 2 + 1];
          u32 wq[4];
          #pragma unroll
          for (int q = 0; q < 4; ++q){
            int cc = c8 * 8 + q * 2;
            float va = eluf(fmaf(d0, dW0[cc],     fmaf(d1, dW0[HD + cc],     db0[cc])));
            float vb = eluf(fmaf(d0, dW0[cc + 1], fmaf(d1, dW0[HD + cc + 1], db0[cc + 1])));
            wq[q] = cvtpk(va, vb);
          }
          *(uint4*)(ldsA + SW(row, c8 * 16)) = make_uint4(wq[0], wq[1], wq[2], wq[3]);
        }
      }
    }
    __syncthreads();   // A: stage visible

    // ---------------- layer 1 (K=128) ----------------
    const f32x4 zz = {0.f, 0.f, 0.f, 0.f};
    f32x4 c1[2][2] = {{zz, zz}, {zz, zz}};
    #pragma unroll
    for (int k0 = 0; k0 < 4; ++k0){
      bf16x8 a0 = *(const bf16x8*)(ldsA + SW(ln,      k0 * 64 + (kq << 4)));
      bf16x8 a1 = *(const bf16x8*)(ldsA + SW(16 + ln, k0 * 64 + (kq << 4)));
      c1[0][0] = __builtin_amdgcn_mfma_f32_16x16x32_bf16(a0, b1f[k0][0], c1[0][0], 0, 0, 0);
      c1[0][1] = __builtin_amdgcn_mfma_f32_16x16x32_bf16(a0, b1f[k0][1], c1[0][1], 0, 0, 0);
      c1[1][0] = __builtin_amdgcn_mfma_f32_16x16x32_bf16(a1, b1f[k0][0], c1[1][0], 0, 0, 0);
      c1[1][1] = __builtin_amdgcn_mfma_f32_16x16x32_bf16(a1, b1f[k0][1], c1[1][1], 0, 0, 0);
    }

    if constexpr (!HAS2){
      // DEC1: r = elu(c1 + b0) -> ldsPQ (f32)
      #pragma unroll
      for (int mi = 0; mi < 2; ++mi)
        #pragma unroll
        for (int nt = 0; nt < 2; ++nt)
          #pragma unroll
          for (int r = 0; r < 4; ++r){
            int row = mi * 16 + kq * 4 + r, col = ncol + nt * 16 + ln;
            *(float*)((char*)ldsPQ + SWF(row, col * 4)) = eluf(c1[mi][nt][r] + b0v[nt]);
          }
      __syncthreads();  // C
    } else {
      // layer-2 weight frags: transient per tile (anti-hoist)
      const u16* w1p = W1c;
      asm volatile("" : "+v"(w1p));
      uint4 b2r[4][2];
      #pragma unroll
      for (int k0 = 0; k0 < 4; ++k0)
        #pragma unroll
        for (int nt = 0; nt < 2; ++nt)
          b2r[k0][nt] = *(const uint4*)(w1p + (((size_t)((k0*4 + kq)*HD + ncol + nt*16 + ln)) << 3));

      // h = elu(c1 + addend + b0) -> ldsH (bf16)
      #pragma unroll
      for (int mi = 0; mi < 2; ++mi)
        #pragma unroll
        for (int nt = 0; nt < 2; ++nt)
          #pragma unroll
          for (int r = 0; r < 4; ++r){
            int row = mi * 16 + kq * 4 + r, col = ncol + nt * 16 + ln;
            float pq = *(const float*)((char*)ldsPQ + SWF(row, col * 4));
            *(u16*)(ldsH + SW(row, col * 2)) = f2bf(eluf(c1[mi][nt][r] + pq + b0v[nt]));
          }
      __syncthreads();  // B: h complete, ldsPQ reads done

      // ---------------- layer 2 ----------------
      f32x4 c2[2][2] = {{zz, zz}, {zz, zz}};
      #pragma unroll
      for (int k0 = 0; k0 < 4; ++k0){
        bf16x8 a0 = *(const bf16x8*)(ldsH + SW(ln,      k0 * 64 + (kq << 4)));
        bf16x8 a1 = *(const bf16x8*)(ldsH + SW(16 + ln, k0 * 64 + (kq << 4)));
        bf16x8 w0 = __builtin_bit_cast(bf16x8, b2r[k0][0]);
        bf16x8 w1 = __builtin_bit_cast(bf16x8, b2r[k0][1]);
        c2[0][0] = __builtin_amdgcn_mfma_f32_16x16x32_bf16(a0, w0, c2[0][0], 0, 0, 0);
        c2[0][1] = __builtin_amdgcn_mfma_f32_16x16x32_bf16(a0, w1, c2[0][1], 0, 0, 0);
        c2[1][0] = __builtin_amdgcn_mfma_f32_16x16x32_bf16(a1, w0, c2[1][0], 0, 0, 0);
        c2[1][1] = __builtin_amdgcn_mfma_f32_16x16x32_bf16(a1, w1, c2[1][1], 0, 0, 0);
      }
      // r = c2 + b1 (DEC2: elu) -> ldsPQ (f32, safe after barrier B)
      #pragma unroll
      for (int mi = 0; mi < 2; ++mi)
        #pragma unroll
        for (int nt = 0; nt < 2; ++nt)
          #pragma unroll
          for (int r = 0; r < 4; ++r){
            int row = mi * 16 + kq * 4 + r, col = ncol + nt * 16 + ln;
            float v = c2[mi][nt][r] + b1v[nt];
            if constexpr (ELU2) v = eluf(v);
            *(float*)((char*)ldsPQ + SWF(row, col * 4)) = v;
          }
      __syncthreads();  // C: r complete
    }

    // ---------------- LN (+ residual) + direct u16 stores ----------------
    #pragma unroll
    for (int rr = 0; rr < 8; ++rr){
      int e = wid * 8 + rr, rg = row0 + e;
      float v0 = *(const float*)((char*)ldsPQ + SWF(e, lane * 4));
      float v1 = *(const float*)((char*)ldsPQ + SWF(e, (64 + lane) * 4));
      float y0, y1;
      if constexpr (HAS2){
        if (rg < n_rows){
          v0 += bf2f(resid[(((size_t)rg) << 7) + lane]);
          v1 += bf2f(resid[(((size_t)rg) << 7) + 64 + lane]);
        }
        float s = v0 + v1, q = v0 * v0 + v1 * v1;
        #pragma unroll
        for (int o = 32; o; o >>= 1){ s += __shfl_xor(s, o); q += __shfl_xor(q, o); }
        float mu  = s * (1.f / 128.f);
        float var = q * (1.f / 128.f) - mu * mu;
        float rs  = rsqrtf(var + 1e-5f);
        y0 = (v0 - mu) * rs * gl0 + bt0;
        y1 = (v1 - mu) * rs * gl1 + bt1;
      } else { y0 = v0; y1 = v1; }
      if (rg < n_rows){
        outp[(((size_t)rg) << 7) + lane]      = f2bf(y0);
        outp[(((size_t)rg) << 7) + 64 + lane] = f2bf(y1);
      }
    }
    __syncthreads();  // D: LN reads done before next stage overwrites ldsPQ/ldsA
  }
}

// out0 = elu(x @ oW + ob)
__global__ void outhead_kernel(const u16* __restrict__ x, const float* __restrict__ oW,
                               const float* __restrict__ ob, float* __restrict__ out){
  int row  = (blockIdx.x * blockDim.x + threadIdx.x) >> 6;
  int lane = threadIdx.x & 63;
  if (row >= NF) return;
  float x0 = bf2f(x[((size_t)row << 7) + lane]);
  float x1 = bf2f(x[((size_t)row << 7) + 64 + lane]);
  float s0 = x0 * oW[lane * 3 + 0] + x1 * oW[(64 + lane) * 3 + 0];
  float s1 = x0 * oW[lane * 3 + 1] + x1 * oW[(64 + lane) * 3 + 1];
  float s2 = x0 * oW[lane * 3 + 2] + x1 * oW[(64 + lane) * 3 + 2];
  #pragma unroll
  for (int o = 32; o; o >>= 1){
    s0 += __shfl_xor(s0, o); s1 += __shfl_xor(s1, o); s2 += __shfl_xor(s2, o);
  }
  if (lane == 0){
    out[row * 3 + 0] = eluf(s0 + ob[0]);
    out[row * 3 + 1] = eluf(s1 + ob[1]);
    out[row * 3 + 2] = eluf(s2 + ob[2]);
  }
}

__global__ void idxcopy_kernel(const int* __restrict__ ei, float* __restrict__ out){
  int i = blockIdx.x * blockDim.x + threadIdx.x;
  if (i < 2 * ECNT) out[i] = (float)ei[i];
}

extern "C" void kernel_launch(void* const* d_in, const int* in_sizes, int n_in,
                              void* d_out, int out_size, void* d_ws, size_t ws_size,
                              hipStream_t stream)
{
  const float* x_in  = (const float*)d_in[0];
  const float* ea_in = (const float*)d_in[1];
  const float* pos_c = (const float*)d_in[2];
  const float* pos_f = (const float*)d_in[3];
  const int*   ei    = (const int*)d_in[4];
  const int*   clus  = (const int*)d_in[5];
  const float* eW0 = (const float*)d_in[7];
  const float* eb0 = (const float*)d_in[8];
  const float* eW1 = (const float*)d_in[9];
  const float* eb1 = (const float*)d_in[10];
  const float* eg  = (const float*)d_in[11];
  const float* ebt = (const float*)d_in[12];
  const float* nW0 = (const float*)d_in[13];
  const float* nb0 = (const float*)d_in[14];
  const float* nW1 = (const float*)d_in[15];
  const float* nb1 = (const float*)d_in[16];
  const float* ng  = (const float*)d_in[17];
  const float* nbt = (const float*)d_in[18];
  const float* dW0 = (const float*)d_in[19];
  const float* db0 = (const float*)d_in[20];
  const float* dW1 = (const float*)d_in[21];
  const float* db1 = (const float*)d_in[22];
  const float* uW0 = (const float*)d_in[23];
  const float* ub0 = (const float*)d_in[24];
  const float* uW1 = (const float*)d_in[25];
  const float* ub1 = (const float*)d_in[26];
  const float* ug  = (const float*)d_in[27];
  const float* ubt = (const float*)d_in[28];
  const float* oW  = (const float*)d_in[29];
  const float* ob  = (const float*)d_in[30];

  char* w = (char*)d_ws;
  auto alloc = [&](size_t bytes) -> char* {
    char* p = w; w += (bytes + 255) & ~(size_t)255; return p;
  };
  u16*   ea_s   = (u16*)alloc((size_t)ECNT * HD * 2);
  u16*   xa     = (u16*)alloc((size_t)NC * HD * 2);
  u16*   xb     = (u16*)alloc((size_t)NF * HD * 2);
  u16*   eac    = (u16*)alloc((size_t)NF * HD * 2);
  float* P      = (float*)alloc((size_t)NF * HD * 4);
  float* Q      = (float*)alloc((size_t)NF * HD * 4);
  float* T      = (float*)alloc((size_t)NF * HD * 4);
  float* XU     = (float*)alloc((size_t)NC * HD * 4);
  int*   deg    = (int*)alloc((size_t)NF * 4);
  int*   rowptr = (int*)alloc((size_t)(NF + 1) * 4);
  int*   cursor = (int*)alloc((size_t)NF * 4);
  int*   perm   = (int*)alloc((size_t)ECNT * 4);
  int*   esrc   = (int*)alloc((size_t)ECNT * 4);
  int*   edst   = (int*)alloc((size_t)ECNT * 4);
  int*   part   = (int*)alloc((size_t)SCB * 4);
  u16*   c_eW0  = (u16*)alloc((size_t)2 * 384 * HD * 2);
  u16*   c_eW1  = (u16*)alloc((size_t)2 * HD * HD * 2);
  u16*   c_nW0  = (u16*)alloc((size_t)2 * 256 * HD * 2);
  u16*   c_nW1  = (u16*)alloc((size_t)2 * HD * HD * 2);
  u16*   c_uW0  = (u16*)alloc((size_t)256 * HD * 2);
  u16*   c_uW1  = (u16*)alloc((size_t)HD * HD * 2);
  u16*   c_dW1  = (u16*)alloc((size_t)HD * HD * 2);

  auto prep = [&](const float* W, u16* o, int K){
    int n = K * HD;
    prep_w_kernel<<<(n + 255) / 256, 256, 0, stream>>>(W, o, K);
  };
  prep(eW0, c_eW0, 384); prep(eW0 + 384 * HD, c_eW0 + 384 * HD, 384);
  prep(eW1, c_eW1, 128); prep(eW1 + HD * HD,  c_eW1 + HD * HD,  128);
  prep(nW0, c_nW0, 256); prep(nW0 + 256 * HD, c_nW0 + 256 * HD, 256);
  prep(nW1, c_nW1, 128); prep(nW1 + HD * HD,  c_nW1 + HD * HD,  128);
  prep(uW0, c_uW0, 256); prep(uW1, c_uW1, 128); prep(dW1, c_dW1, 128);

  f32_to_bf16_vec<<<(NC * HD / 8 + 255) / 256, 256, 0, stream>>>(x_in, xa, NC * HD / 8);

  hipMemsetAsync(deg, 0, (size_t)NF * 4, stream);
  deg_kernel<<<(ECNT + 255) / 256, 256, 0, stream>>>(ei, deg);
  scanA_kernel<<<NB_SCAN, SCB, 0, stream>>>(deg, part);
  scanB_kernel<<<1, SCB, 0, stream>>>(part);
  scanC_kernel<<<NB_SCAN, SCB, 0, stream>>>(deg, part, rowptr);
  hipMemcpyAsync(cursor, rowptr, (size_t)NF * 4, hipMemcpyDeviceToDevice, stream);
  build_perm_kernel<<<(ECNT + 255) / 256, 256, 0, stream>>>(ei, cursor, perm, esrc, edst);
  permute_ea_kernel<<<(ECNT * 16 + 255) / 256, 256, 0, stream>>>(ea_in, perm, ea_s);

  auto grd = [](int rows){ int t = (rows + 31) / 32; return t < 1024 ? t : 1024; };
  const int KS = 16 * HD * 8;   // u16 offset of one 128-K slice in chunked layout

  auto mp_iter = [&](u16* x, int n, int i){
    lin_kernel<3><<<grd(n), 256, 0, stream>>>(
      c_eW0 + (size_t)i*384*HD, c_eW0 + (size_t)i*384*HD + KS, c_nW0 + (size_t)i*256*HD,
      x, P, Q, T, n);
    mlp_kernel<M_EDGE><<<grd(ECNT), 256, 0, stream>>>(
      c_eW0 + (size_t)i*384*HD + 2*KS, c_eW1 + (size_t)i*HD*HD,
      eb0 + i*HD, eb1 + i*HD, eg + i*HD, ebt + i*HD,
      ea_s, P, Q, ea_s, esrc, edst, nullptr, nullptr, nullptr,
      ea_s, ECNT, nullptr, nullptr, nullptr, nullptr);
    mlp_kernel<M_NODE><<<grd(n), 256, 0, stream>>>(
      c_nW0 + (size_t)i*256*HD + KS, c_nW1 + (size_t)i*HD*HD,
      nb0 + i*HD, nb1 + i*HD, ng + i*HD, nbt + i*HD,
      nullptr, T, nullptr, x, nullptr, nullptr, rowptr, ea_s, nullptr,
      x, n, nullptr, nullptr, nullptr, nullptr);
  };

  // ---- pass 1 on xa ----
  mp_iter(xa, NC, 0);
  mp_iter(xa, NC, 1);

  // ---- decoder (seg_mean over arange(NF) is identity) ----
  lin_kernel<1><<<grd(NC), 256, 0, stream>>>(
    c_uW0 + KS, nullptr, nullptr, xa, XU, nullptr, nullptr, NC);
  mlp_kernel<M_DEC1><<<grd(NF), 256, 0, stream>>>(
    c_dW1, nullptr, db1, nullptr, nullptr, nullptr,
    nullptr, nullptr, nullptr, nullptr, nullptr, nullptr, nullptr, nullptr, clus,
    eac, NF, dW0, db0, pos_c, pos_f);
  mlp_kernel<M_DEC2><<<grd(NF), 256, 0, stream>>>(
    c_uW0, c_uW1, ub0, ub1, ug, ubt,
    eac, XU, nullptr, eac, nullptr, nullptr, nullptr, nullptr, clus,
    xb, NF, nullptr, nullptr, nullptr, nullptr);

  // ---- pass 2 on xb ----
  mp_iter(xb, NF, 0);
  mp_iter(xb, NF, 1);

  float* out = (float*)d_out;
  outhead_kernel<<<(NF + 3) / 4, 256, 0, stream>>>(xb, oW, ob, out);
  idxcopy_kernel<<<(2 * ECNT + 255) / 256, 256, 0, stream>>>(ei, out + (size_t)NF * OUTD);
}

// Round 5
// 1737.113 us; speedup vs baseline: 1.5204x; 1.5204x over previous
//
#include <hip/hip_runtime.h>

// Decoder_48378511622552 — CSR-sorted, bf16, K=128 MFMA fused GNN decoder (gfx950)
// Round 5: bf16 addend tables (L3-resident gathers) + R4 VALU wins + resid-from-LDS.

#define HD   128
#define NC   50000
#define NF   150000
#define ECNT 400000
#define OUTD 3
#define SCB  512
#define NB_SCAN ((NF + SCB - 1) / SCB)   // 293

typedef unsigned short u16;
typedef unsigned int   u32;
typedef short bf16x8 __attribute__((ext_vector_type(8)));
typedef float f32x4  __attribute__((ext_vector_type(4)));

__device__ __forceinline__ float bf2f(u32 u){ return __uint_as_float(u << 16); }
__device__ __forceinline__ u32 cvtpk(float a, float b){   // lo = bf16(a), hi = bf16(b)
  u32 r; asm("v_cvt_pk_bf16_f32 %0, %1, %2" : "=v"(r) : "v"(a), "v"(b)); return r;
}
__device__ __forceinline__ u16 f2bf(float f){ return (u16)cvtpk(f, f); }
__device__ __forceinline__ u32 addpk(u32 a, u32 b){
  return cvtpk(bf2f(a & 0xffffu) + bf2f(b & 0xffffu),
               __uint_as_float(a & 0xffff0000u) + __uint_as_float(b & 0xffff0000u));
}
__device__ __forceinline__ float eluf(float x){ return x > 0.f ? x : __expf(x) - 1.f; }
// swizzle for bf16 [32][256B] tiles
__device__ __forceinline__ int SW(int row, int byte){ return row * 256 + (byte ^ ((row & 7) << 4)); }

// ---------------- prep kernels ----------------

// chunked bf16 weights: out[((k>>3)*128 + j)*8 + (k&7)] = bf16(W[k*128 + j])
__global__ void prep_w_kernel(const float* __restrict__ W, u16* __restrict__ out, int K){
  int idx = blockIdx.x * blockDim.x + threadIdx.x;
  if (idx >= K * HD) return;
  int k = idx / HD, j = idx % HD;
  out[(((k >> 3) * HD + j) << 3) + (k & 7)] = f2bf(W[k * HD + j]);
}

__global__ void f32_to_bf16_vec(const float* __restrict__ in, u16* __restrict__ out, int n8){
  int i = blockIdx.x * blockDim.x + threadIdx.x;
  if (i >= n8) return;
  float4 f0 = ((const float4*)in)[i * 2];
  float4 f1 = ((const float4*)in)[i * 2 + 1];
  ((uint4*)out)[i] = make_uint4(cvtpk(f0.x,f0.y), cvtpk(f0.z,f0.w), cvtpk(f1.x,f1.y), cvtpk(f1.z,f1.w));
}

__global__ void deg_kernel(const int* __restrict__ ei, int* __restrict__ deg){
  int e = blockIdx.x * blockDim.x + threadIdx.x;
  if (e < ECNT) atomicAdd(&deg[ei[ECNT + e]], 1);
}

__global__ void scanA_kernel(const int* __restrict__ deg, int* __restrict__ part){
  __shared__ int s[SCB];
  int t = threadIdx.x, i = blockIdx.x * SCB + t;
  s[t] = (i < NF) ? deg[i] : 0;
  __syncthreads();
  for (int off = SCB/2; off; off >>= 1){ if (t < off) s[t] += s[t + off]; __syncthreads(); }
  if (t == 0) part[blockIdx.x] = s[0];
}

__global__ void scanB_kernel(int* __restrict__ part){
  __shared__ int s[SCB];
  int t = threadIdx.x;
  int v = (t < NB_SCAN) ? part[t] : 0;
  s[t] = v; __syncthreads();
  for (int off = 1; off < SCB; off <<= 1){
    int x = (t >= off) ? s[t - off] : 0;
    __syncthreads(); s[t] += x; __syncthreads();
  }
  if (t < NB_SCAN) part[t] = s[t] - v;   // exclusive
}

__global__ void scanC_kernel(const int* __restrict__ deg, const int* __restrict__ part,
                             int* __restrict__ rowptr){
  __shared__ int s[SCB];
  int t = threadIdx.x, i = blockIdx.x * SCB + t;
  int v = (i < NF) ? deg[i] : 0;
  s[t] = v; __syncthreads();
  for (int off = 1; off < SCB; off <<= 1){
    int x = (t >= off) ? s[t - off] : 0;
    __syncthreads(); s[t] += x; __syncthreads();
  }
  int excl = part[blockIdx.x] + s[t] - v;
  if (i < NF) rowptr[i] = excl;
  if (i == NF - 1) rowptr[NF] = excl + v;
}

__global__ void build_perm_kernel(const int* __restrict__ ei, int* __restrict__ cursor,
                                  int* __restrict__ perm, int* __restrict__ esrc,
                                  int* __restrict__ edst){
  int e = blockIdx.x * blockDim.x + threadIdx.x;
  if (e >= ECNT) return;
  int sI = ei[e], d = ei[ECNT + e];
  int p = atomicAdd(&cursor[d], 1);
  perm[p] = e; esrc[p] = sI; edst[p] = d;
}

__global__ void permute_ea_kernel(const float* __restrict__ ea_in, const int* __restrict__ perm,
                                  u16* __restrict__ ea_s){
  int i = blockIdx.x * blockDim.x + threadIdx.x;
  if (i >= ECNT * 16) return;
  int p = i >> 4, c = i & 15;
  int e = perm[p];
  const float4* src = (const float4*)(ea_in + (size_t)e * HD + c * 8);
  float4 f0 = src[0], f1 = src[1];
  ((uint4*)ea_s)[(size_t)p * 16 + c] =
      make_uint4(cvtpk(f0.x,f0.y), cvtpk(f0.z,f0.w), cvtpk(f1.x,f1.y), cvtpk(f1.z,f1.w));
}

// ---------------- fused LIN (1 or 3 outputs): o[w] = x @ W[w], bf16 out ----------------
template<int NOUT>
__global__ __launch_bounds__(256, 4)
void lin_kernel(const u16* __restrict__ Wa, const u16* __restrict__ Wb, const u16* __restrict__ Wc,
                const u16* __restrict__ x, u16* __restrict__ oA, u16* __restrict__ oB,
                u16* __restrict__ oC, int n_rows)
{
  __shared__ __align__(16) char ldsA[32 * 256];
  const int tid = threadIdx.x, lane = tid & 63, wid = tid >> 6;
  const int ln = lane & 15, kq = lane >> 4, ncol = wid * 32;
  const int tiles = (n_rows + 31) >> 5;

  for (int tile = blockIdx.x; tile < tiles; tile += gridDim.x){
    const int row0 = tile << 5;
    #pragma unroll
    for (int c = 0; c < 2; ++c){
      int i = tid + c * 256, row = i >> 4, kk = i & 15, rg = row0 + row;
      if (rg < n_rows)
        *(uint4*)(ldsA + SW(row, kk * 16)) = *(const uint4*)(x + (((size_t)rg) << 7) + (kk << 3));
    }
    __syncthreads();
    bf16x8 af[4][2];
    #pragma unroll
    for (int k0 = 0; k0 < 4; ++k0){
      af[k0][0] = *(const bf16x8*)(ldsA + SW(ln,      k0 * 64 + (kq << 4)));
      af[k0][1] = *(const bf16x8*)(ldsA + SW(16 + ln, k0 * 64 + (kq << 4)));
    }
    __syncthreads();   // all frag reads done -> next stage may overwrite

    const u16* Ws[3] = {Wa, Wb, Wc};
    u16*       Os[3] = {oA, oB, oC};
    const f32x4 zz = {0.f, 0.f, 0.f, 0.f};
    #pragma unroll
    for (int w = 0; w < NOUT; ++w){
      const u16* wp = Ws[w];
      asm volatile("" : "+v"(wp));   // anti-hoist: keep b-frags transient per tile
      uint4 bf[4][2];
      #pragma unroll
      for (int k0 = 0; k0 < 4; ++k0)
        #pragma unroll
        for (int nt = 0; nt < 2; ++nt)
          bf[k0][nt] = *(const uint4*)(wp + (((size_t)((k0*4 + kq)*HD + ncol + nt*16 + ln)) << 3));
      f32x4 cc[2][2] = {{zz, zz}, {zz, zz}};
      #pragma unroll
      for (int k0 = 0; k0 < 4; ++k0){
        bf16x8 w0 = __builtin_bit_cast(bf16x8, bf[k0][0]);
        bf16x8 w1 = __builtin_bit_cast(bf16x8, bf[k0][1]);
        cc[0][0] = __builtin_amdgcn_mfma_f32_16x16x32_bf16(af[k0][0], w0, cc[0][0], 0, 0, 0);
        cc[0][1] = __builtin_amdgcn_mfma_f32_16x16x32_bf16(af[k0][0], w1, cc[0][1], 0, 0, 0);
        cc[1][0] = __builtin_amdgcn_mfma_f32_16x16x32_bf16(af[k0][1], w0, cc[1][0], 0, 0, 0);
        cc[1][1] = __builtin_amdgcn_mfma_f32_16x16x32_bf16(af[k0][1], w1, cc[1][1], 0, 0, 0);
      }
      u16* op = Os[w];
      #pragma unroll
      for (int mi = 0; mi < 2; ++mi)
        #pragma unroll
        for (int nt = 0; nt < 2; ++nt)
          #pragma unroll
          for (int r = 0; r < 4; ++r){
            int rg = row0 + mi * 16 + kq * 4 + r;
            if (rg < n_rows) op[(size_t)rg * HD + ncol + nt * 16 + ln] = f2bf(cc[mi][nt][r]);
          }
    }
  }
}

// ---------------- unified fused K=128 MFMA MLP ----------------
enum { M_DEC1 = 0, M_EDGE = 1, M_NODE = 2, M_DEC2 = 3 };

// EDGE: A = ea;  h = elu(A@W0 + P[src]+Q[dst] + b0); o = h@W1 + b1;       out = LN(A + o)
// NODE: A = CSR-mean(ea); h = elu(A@W0 + T[row] + b0); o = h@W1 + b1;    out = LN(x + o)
// DEC2: A = eac; h = elu(A@W0 + XU[clus] + b0); o = elu(h@W1 + b1);      out = LN(A + o)
// DEC1: A = elu(delta@dW0+db0) inline; out = elu(A@W0 + b0)
template<int MODE>
__global__ __launch_bounds__(256, 4)
void mlp_kernel(const u16* __restrict__ W0c, const u16* __restrict__ W1c,
                const float* __restrict__ b0, const float* __restrict__ b1,
                const float* __restrict__ gw, const float* __restrict__ bw,
                const u16* __restrict__ tabA, const u16* __restrict__ addP,
                const u16* __restrict__ addQ, const u16* __restrict__ resid,
                const int* __restrict__ esrc, const int* __restrict__ edst,
                const int* __restrict__ rowptr, const u16* __restrict__ eatab,
                const int* __restrict__ clus,
                u16* __restrict__ outp, int n_rows,
                const float* __restrict__ dW0, const float* __restrict__ db0,
                const float* __restrict__ pos_c, const float* __restrict__ pos_f)
{
  constexpr bool HAS2   = (MODE != M_DEC1);
  constexpr bool ELU2   = (MODE == M_DEC2);
  constexpr bool RESLDS = (MODE == M_EDGE || MODE == M_DEC2);   // residual == A-tile in ldsA

  __shared__ __align__(16) char ldsA [32 * 256];          // bf16 A tile (also residual)
  __shared__ __align__(16) char ldsPQ[32 * 256];          // bf16 addend / r staging
  __shared__ __align__(16) char ldsH [HAS2 ? 32 * 256 : 16];

  const int tid  = threadIdx.x;
  const int lane = tid & 63;
  const int wid  = tid >> 6;          // 0..3
  const int ln   = lane & 15, kq = lane >> 4;
  const int ncol = wid * 32;

  bf16x8 b1f[4][2];
  #pragma unroll
  for (int k0 = 0; k0 < 4; ++k0)
    #pragma unroll
    for (int nt = 0; nt < 2; ++nt)
      b1f[k0][nt] = *(const bf16x8*)(W0c + (((size_t)((k0*4 + kq)*HD + ncol + nt*16 + ln)) << 3));

  float b0v[2], b1v[2] = {0.f, 0.f};
  #pragma unroll
  for (int nt = 0; nt < 2; ++nt) b0v[nt] = b0[ncol + nt*16 + ln];
  float gl0 = 0.f, gl1 = 0.f, bt0 = 0.f, bt1 = 0.f;
  if constexpr (HAS2){
    #pragma unroll
    for (int nt = 0; nt < 2; ++nt) b1v[nt] = b1[ncol + nt*16 + ln];
    gl0 = gw[lane]; gl1 = gw[64 + lane]; bt0 = bw[lane]; bt1 = bw[64 + lane];
  }

  const int tiles = (n_rows + 31) >> 5;

  for (int tile = blockIdx.x; tile < tiles; tile += gridDim.x){
    const int row0 = tile << 5;

    // ---------------- stage ----------------
    if constexpr (MODE == M_EDGE){
      #pragma unroll
      for (int c = 0; c < 2; ++c){           // ea tile + (P[src]+Q[dst]) addend, both bf16
        int i = tid + c * 256, row = i >> 4, kk = i & 15, rg = row0 + row;   // ECNT%32==0
        *(uint4*)(ldsA + SW(row, kk * 16)) =
            *(const uint4*)(tabA + (((size_t)rg) << 7) + (kk << 3));
        int sI = esrc[rg], dI = edst[rg];
        uint4 p = *(const uint4*)(addP + (((size_t)sI) << 7) + (kk << 3));
        uint4 q = *(const uint4*)(addQ + (((size_t)dI) << 7) + (kk << 3));
        *(uint4*)(ldsPQ + SW(row, kk * 16)) =
            make_uint4(addpk(p.x,q.x), addpk(p.y,q.y), addpk(p.z,q.z), addpk(p.w,q.w));
      }
    } else if constexpr (MODE == M_DEC2){
      #pragma unroll
      for (int c = 0; c < 2; ++c){
        int i = tid + c * 256, row = i >> 4, kk = i & 15, rg = row0 + row;
        if (rg < n_rows){
          *(uint4*)(ldsA + SW(row, kk * 16)) =
              *(const uint4*)(tabA + (((size_t)rg) << 7) + (kk << 3));
          int cl = clus[rg];
          *(uint4*)(ldsPQ + SW(row, kk * 16)) =
              *(const uint4*)(addP + (((size_t)cl) << 7) + (kk << 3));
        }
      }
    } else if constexpr (MODE == M_NODE){
      #pragma unroll
      for (int c = 0; c < 2; ++c){           // T[row] addend, bf16
        int i = tid + c * 256, row = i >> 4, kk = i & 15, rg = row0 + row;
        if (rg < n_rows)
          *(uint4*)(ldsPQ + SW(row, kk * 16)) =
              *(const uint4*)(addP + (((size_t)rg) << 7) + (kk << 3));
      }
      // CSR mean of ea -> ldsA; wave handles 8 nodes, lane covers cols (2*lane, 2*lane+1)
      for (int s = 0; s < 8; ++s){
        int nd = wid * 8 + s, rg = row0 + nd;
        if (rg < n_rows){
          int rp0 = rowptr[rg], rp1 = rowptr[rg + 1];
          float s0 = 0.f, s1 = 0.f;
          int i2 = rp0;
          for (; i2 + 1 < rp1; i2 += 2){
            u32 ua = *(const u32*)(eatab + (((size_t)i2) << 7) + (lane << 1));
            u32 ub = *(const u32*)(eatab + (((size_t)(i2+1)) << 7) + (lane << 1));
            s0 += bf2f(ua & 0xffffu) + bf2f(ub & 0xffffu);
            s1 += bf2f(ua >> 16)     + bf2f(ub >> 16);
          }
          if (i2 < rp1){
            u32 ua = *(const u32*)(eatab + (((size_t)i2) << 7) + (lane << 1));
            s0 += bf2f(ua & 0xffffu); s1 += bf2f(ua >> 16);
          }
          int dg = rp1 - rp0;
          float rd = 1.f / (float)(dg > 0 ? dg : 1);
          *(u32*)(ldsA + SW(nd, lane << 2)) = cvtpk(s0 * rd, s1 * rd);
        }
      }
    } else { // M_DEC1: inline h1 = elu(delta @ dW0 + db0) -> ldsA
      #pragma unroll
      for (int c = 0; c < 2; ++c){
        int i = tid + c * 256, row = i >> 4, c8 = i & 15, rg = row0 + row;
        if (rg < n_rows){
          int cl = clus[rg];
          float d0 = pos_c[cl * 2]     - pos_f[rg * 2];
          float d1 = pos_c[cl * 2 + 1] - pos_f[rg * 2 + 1];
          u32 wq[4];
          #pragma unroll
          for (int q = 0; q < 4; ++q){
            int cc = c8 * 8 + q * 2;
            float va = eluf(fmaf(d0, dW0[cc],     fmaf(d1, dW0[HD + cc],     db0[cc])));
            float vb = eluf(fmaf(d0, dW0[cc + 1], fmaf(d1, dW0[HD + cc + 1], db0[cc + 1])));
            wq[q] = cvtpk(va, vb);
          }
          *(uint4*)(ldsA + SW(row, c8 * 16)) = make_uint4(wq[0], wq[1], wq[2], wq[3]);
        }
      }
    }
    __syncthreads();   // A: stage visible

    // ---------------- layer 1 (K=128) ----------------
    const f32x4 zz = {0.f, 0.f, 0.f, 0.f};
    f32x4 c1[2][2] = {{zz, zz}, {zz, zz}};
    #pragma unroll
    for (int k0 = 0; k0 < 4; ++k0){
      bf16x8 a0 = *(const bf16x8*)(ldsA + SW(ln,      k0 * 64 + (kq << 4)));
      bf16x8 a1 = *(const bf16x8*)(ldsA + SW(16 + ln, k0 * 64 + (kq << 4)));
      c1[0][0] = __builtin_amdgcn_mfma_f32_16x16x32_bf16(a0, b1f[k0][0], c1[0][0], 0, 0, 0);
      c1[0][1] = __builtin_amdgcn_mfma_f32_16x16x32_bf16(a0, b1f[k0][1], c1[0][1], 0, 0, 0);
      c1[1][0] = __builtin_amdgcn_mfma_f32_16x16x32_bf16(a1, b1f[k0][0], c1[1][0], 0, 0, 0);
      c1[1][1] = __builtin_amdgcn_mfma_f32_16x16x32_bf16(a1, b1f[k0][1], c1[1][1], 0, 0, 0);
    }

    if constexpr (!HAS2){
      // DEC1: r = elu(c1 + b0) -> ldsPQ (bf16)
      #pragma unroll
      for (int mi = 0; mi < 2; ++mi)
        #pragma unroll
        for (int nt = 0; nt < 2; ++nt)
          #pragma unroll
          for (int r = 0; r < 4; ++r){
            int row = mi * 16 + kq * 4 + r, col = ncol + nt * 16 + ln;
            *(u16*)(ldsPQ + SW(row, col * 2)) = f2bf(eluf(c1[mi][nt][r] + b0v[nt]));
          }
      __syncthreads();  // C
    } else {
      // layer-2 weight frags: transient per tile (anti-hoist)
      const u16* w1p = W1c;
      asm volatile("" : "+v"(w1p));
      uint4 b2r[4][2];
      #pragma unroll
      for (int k0 = 0; k0 < 4; ++k0)
        #pragma unroll
        for (int nt = 0; nt < 2; ++nt)
          b2r[k0][nt] = *(const uint4*)(w1p + (((size_t)((k0*4 + kq)*HD + ncol + nt*16 + ln)) << 3));

      // h = elu(c1 + addend + b0) -> ldsH (bf16)
      #pragma unroll
      for (int mi = 0; mi < 2; ++mi)
        #pragma unroll
        for (int nt = 0; nt < 2; ++nt)
          #pragma unroll
          for (int r = 0; r < 4; ++r){
            int row = mi * 16 + kq * 4 + r, col = ncol + nt * 16 + ln;
            float pq = bf2f(*(const u16*)(ldsPQ + SW(row, col * 2)));
            *(u16*)(ldsH + SW(row, col * 2)) = f2bf(eluf(c1[mi][nt][r] + pq + b0v[nt]));
          }
      __syncthreads();  // B: h complete, ldsPQ reads done

      // ---------------- layer 2 ----------------
      f32x4 c2[2][2] = {{zz, zz}, {zz, zz}};
      #pragma unroll
      for (int k0 = 0; k0 < 4; ++k0){
        bf16x8 a0 = *(const bf16x8*)(ldsH + SW(ln,      k0 * 64 + (kq << 4)));
        bf16x8 a1 = *(const bf16x8*)(ldsH + SW(16 + ln, k0 * 64 + (kq << 4)));
        bf16x8 w0 = __builtin_bit_cast(bf16x8, b2r[k0][0]);
        bf16x8 w1 = __builtin_bit_cast(bf16x8, b2r[k0][1]);
        c2[0][0] = __builtin_amdgcn_mfma_f32_16x16x32_bf16(a0, w0, c2[0][0], 0, 0, 0);
        c2[0][1] = __builtin_amdgcn_mfma_f32_16x16x32_bf16(a0, w1, c2[0][1], 0, 0, 0);
        c2[1][0] = __builtin_amdgcn_mfma_f32_16x16x32_bf16(a1, w0, c2[1][0], 0, 0, 0);
        c2[1][1] = __builtin_amdgcn_mfma_f32_16x16x32_bf16(a1, w1, c2[1][1], 0, 0, 0);
      }
      // r = c2 + b1 (DEC2: elu) -> ldsPQ (safe after barrier B)
      #pragma unroll
      for (int mi = 0; mi < 2; ++mi)
        #pragma unroll
        for (int nt = 0; nt < 2; ++nt)
          #pragma unroll
          for (int r = 0; r < 4; ++r){
            int row = mi * 16 + kq * 4 + r, col = ncol + nt * 16 + ln;
            float v = c2[mi][nt][r] + b1v[nt];
            if constexpr (ELU2) v = eluf(v);
            *(u16*)(ldsPQ + SW(row, col * 2)) = f2bf(v);
          }
      __syncthreads();  // C: r complete
    }

    // ---------------- LN (+ residual) + direct u16 stores ----------------
    #pragma unroll
    for (int rr = 0; rr < 8; ++rr){
      int e = wid * 8 + rr, rg = row0 + e;
      float v0 = bf2f(*(const u16*)(ldsPQ + SW(e, lane * 2)));
      float v1 = bf2f(*(const u16*)(ldsPQ + SW(e, (64 + lane) * 2)));
      float y0, y1;
      if constexpr (HAS2){
        if constexpr (RESLDS){
          v0 += bf2f(*(const u16*)(ldsA + SW(e, lane * 2)));
          v1 += bf2f(*(const u16*)(ldsA + SW(e, (64 + lane) * 2)));
        } else if (rg < n_rows){
          v0 += bf2f(resid[(((size_t)rg) << 7) + lane]);
          v1 += bf2f(resid[(((size_t)rg) << 7) + 64 + lane]);
        }
        float s = v0 + v1, q = v0 * v0 + v1 * v1;
        #pragma unroll
        for (int o = 32; o; o >>= 1){ s += __shfl_xor(s, o); q += __shfl_xor(q, o); }
        float mu  = s * (1.f / 128.f);
        float var = q * (1.f / 128.f) - mu * mu;
        float rs  = rsqrtf(var + 1e-5f);
        y0 = (v0 - mu) * rs * gl0 + bt0;
        y1 = (v1 - mu) * rs * gl1 + bt1;
      } else { y0 = v0; y1 = v1; }
      if (rg < n_rows){
        outp[(((size_t)rg) << 7) + lane]      = f2bf(y0);
        outp[(((size_t)rg) << 7) + 64 + lane] = f2bf(y1);
      }
    }
    __syncthreads();  // D: LN reads done before next stage overwrites ldsA/ldsPQ
  }
}

// out0 = elu(x @ oW + ob)
__global__ void outhead_kernel(const u16* __restrict__ x, const float* __restrict__ oW,
                               const float* __restrict__ ob, float* __restrict__ out){
  int row  = (blockIdx.x * blockDim.x + threadIdx.x) >> 6;
  int lane = threadIdx.x & 63;
  if (row >= NF) return;
  float x0 = bf2f(x[((size_t)row << 7) + lane]);
  float x1 = bf2f(x[((size_t)row << 7) + 64 + lane]);
  float s0 = x0 * oW[lane * 3 + 0] + x1 * oW[(64 + lane) * 3 + 0];
  float s1 = x0 * oW[lane * 3 + 1] + x1 * oW[(64 + lane) * 3 + 1];
  float s2 = x0 * oW[lane * 3 + 2] + x1 * oW[(64 + lane) * 3 + 2];
  #pragma unroll
  for (int o = 32; o; o >>= 1){
    s0 += __shfl_xor(s0, o); s1 += __shfl_xor(s1, o); s2 += __shfl_xor(s2, o);
  }
  if (lane == 0){
    out[row * 3 + 0] = eluf(s0 + ob[0]);
    out[row * 3 + 1] = eluf(s1 + ob[1]);
    out[row * 3 + 2] = eluf(s2 + ob[2]);
  }
}

__global__ void idxcopy_kernel(const int* __restrict__ ei, float* __restrict__ out){
  int i = blockIdx.x * blockDim.x + threadIdx.x;
  if (i < 2 * ECNT) out[i] = (float)ei[i];
}

extern "C" void kernel_launch(void* const* d_in, const int* in_sizes, int n_in,
                              void* d_out, int out_size, void* d_ws, size_t ws_size,
                              hipStream_t stream)
{
  const float* x_in  = (const float*)d_in[0];
  const float* ea_in = (const float*)d_in[1];
  const float* pos_c = (const float*)d_in[2];
  const float* pos_f = (const float*)d_in[3];
  const int*   ei    = (const int*)d_in[4];
  const int*   clus  = (const int*)d_in[5];
  const float* eW0 = (const float*)d_in[7];
  const float* eb0 = (const float*)d_in[8];
  const float* eW1 = (const float*)d_in[9];
  const float* eb1 = (const float*)d_in[10];
  const float* eg  = (const float*)d_in[11];
  const float* ebt = (const float*)d_in[12];
  const float* nW0 = (const float*)d_in[13];
  const float* nb0 = (const float*)d_in[14];
  const float* nW1 = (const float*)d_in[15];
  const float* nb1 = (const float*)d_in[16];
  const float* ng  = (const float*)d_in[17];
  const float* nbt = (const float*)d_in[18];
  const float* dW0 = (const float*)d_in[19];
  const float* db0 = (const float*)d_in[20];
  const float* dW1 = (const float*)d_in[21];
  const float* db1 = (const float*)d_in[22];
  const float* uW0 = (const float*)d_in[23];
  const float* ub0 = (const float*)d_in[24];
  const float* uW1 = (const float*)d_in[25];
  const float* ub1 = (const float*)d_in[26];
  const float* ug  = (const float*)d_in[27];
  const float* ubt = (const float*)d_in[28];
  const float* oW  = (const float*)d_in[29];
  const float* ob  = (const float*)d_in[30];

  char* w = (char*)d_ws;
  auto alloc = [&](size_t bytes) -> char* {
    char* p = w; w += (bytes + 255) & ~(size_t)255; return p;
  };
  u16*   ea_s   = (u16*)alloc((size_t)ECNT * HD * 2);
  u16*   xa     = (u16*)alloc((size_t)NC * HD * 2);
  u16*   xb     = (u16*)alloc((size_t)NF * HD * 2);
  u16*   eac    = (u16*)alloc((size_t)NF * HD * 2);
  u16*   P      = (u16*)alloc((size_t)NF * HD * 2);
  u16*   Q      = (u16*)alloc((size_t)NF * HD * 2);
  u16*   T      = (u16*)alloc((size_t)NF * HD * 2);
  u16*   XU     = (u16*)alloc((size_t)NC * HD * 2);
  int*   deg    = (int*)alloc((size_t)NF * 4);
  int*   rowptr = (int*)alloc((size_t)(NF + 1) * 4);
  int*   cursor = (int*)alloc((size_t)NF * 4);
  int*   perm   = (int*)alloc((size_t)ECNT * 4);
  int*   esrc   = (int*)alloc((size_t)ECNT * 4);
  int*   edst   = (int*)alloc((size_t)ECNT * 4);
  int*   part   = (int*)alloc((size_t)SCB * 4);
  u16*   c_eW0  = (u16*)alloc((size_t)2 * 384 * HD * 2);
  u16*   c_eW1  = (u16*)alloc((size_t)2 * HD * HD * 2);
  u16*   c_nW0  = (u16*)alloc((size_t)2 * 256 * HD * 2);
  u16*   c_nW1  = (u16*)alloc((size_t)2 * HD * HD * 2);
  u16*   c_uW0  = (u16*)alloc((size_t)256 * HD * 2);
  u16*   c_uW1  = (u16*)alloc((size_t)HD * HD * 2);
  u16*   c_dW1  = (u16*)alloc((size_t)HD * HD * 2);

  auto prep = [&](const float* W, u16* o, int K){
    int n = K * HD;
    prep_w_kernel<<<(n + 255) / 256, 256, 0, stream>>>(W, o, K);
  };
  prep(eW0, c_eW0, 384); prep(eW0 + 384 * HD, c_eW0 + 384 * HD, 384);
  prep(eW1, c_eW1, 128); prep(eW1 + HD * HD,  c_eW1 + HD * HD,  128);
  prep(nW0, c_nW0, 256); prep(nW0 + 256 * HD, c_nW0 + 256 * HD, 256);
  prep(nW1, c_nW1, 128); prep(nW1 + HD * HD,  c_nW1 + HD * HD,  128);
  prep(uW0, c_uW0, 256); prep(uW1, c_uW1, 128); prep(dW1, c_dW1, 128);

  f32_to_bf16_vec<<<(NC * HD / 8 + 255) / 256, 256, 0, stream>>>(x_in, xa, NC * HD / 8);

  hipMemsetAsync(deg, 0, (size_t)NF * 4, stream);
  deg_kernel<<<(ECNT + 255) / 256, 256, 0, stream>>>(ei, deg);
  scanA_kernel<<<NB_SCAN, SCB, 0, stream>>>(deg, part);
  scanB_kernel<<<1, SCB, 0, stream>>>(part);
  scanC_kernel<<<NB_SCAN, SCB, 0, stream>>>(deg, part, rowptr);
  hipMemcpyAsync(cursor, rowptr, (size_t)NF * 4, hipMemcpyDeviceToDevice, stream);
  build_perm_kernel<<<(ECNT + 255) / 256, 256, 0, stream>>>(ei, cursor, perm, esrc, edst);
  permute_ea_kernel<<<(ECNT * 16 + 255) / 256, 256, 0, stream>>>(ea_in, perm, ea_s);

  auto grd = [](int rows){ int t = (rows + 31) / 32; return t < 1024 ? t : 1024; };
  const int KS = 16 * HD * 8;   // u16 offset of one 128-K slice in chunked layout

  auto mp_iter = [&](u16* x, int n, int i){
    lin_kernel<3><<<grd(n), 256, 0, stream>>>(
      c_eW0 + (size_t)i*384*HD, c_eW0 + (size_t)i*384*HD + KS, c_nW0 + (size_t)i*256*HD,
      x, P, Q, T, n);
    mlp_kernel<M_EDGE><<<grd(ECNT), 256, 0, stream>>>(
      c_eW0 + (size_t)i*384*HD + 2*KS, c_eW1 + (size_t)i*HD*HD,
      eb0 + i*HD, eb1 + i*HD, eg + i*HD, ebt + i*HD,
      ea_s, P, Q, nullptr, esrc, edst, nullptr, nullptr, nullptr,
      ea_s, ECNT, nullptr, nullptr, nullptr, nullptr);
    mlp_kernel<M_NODE><<<grd(n), 256, 0, stream>>>(
      c_nW0 + (size_t)i*256*HD + KS, c_nW1 + (size_t)i*HD*HD,
      nb0 + i*HD, nb1 + i*HD, ng + i*HD, nbt + i*HD,
      nullptr, T, nullptr, x, nullptr, nullptr, rowptr, ea_s, nullptr,
      x, n, nullptr, nullptr, nullptr, nullptr);
  };

  // ---- pass 1 on xa ----
  mp_iter(xa, NC, 0);
  mp_iter(xa, NC, 1);

  // ---- decoder (seg_mean over arange(NF) is identity) ----
  lin_kernel<1><<<grd(NC), 256, 0, stream>>>(
    c_uW0 + KS, nullptr, nullptr, xa, XU, nullptr, nullptr, NC);
  mlp_kernel<M_DEC1><<<grd(NF), 256, 0, stream>>>(
    c_dW1, nullptr, db1, nullptr, nullptr, nullptr,
    nullptr, nullptr, nullptr, nullptr, nullptr, nullptr, nullptr, nullptr, clus,
    eac, NF, dW0, db0, pos_c, pos_f);
  mlp_kernel<M_DEC2><<<grd(NF), 256, 0, stream>>>(
    c_uW0, c_uW1, ub0, ub1, ug, ubt,
    eac, XU, nullptr, nullptr, nullptr, nullptr, nullptr, nullptr, clus,
    xb, NF, nullptr, nullptr, nullptr, nullptr);

  // ---- pass 2 on xb ----
  mp_iter(xb, NF, 0);
  mp_iter(xb, NF, 1);

  float* out = (float*)d_out;
  outhead_kernel<<<(NF + 3) / 4, 256, 0, stream>>>(xb, oW, ob, out);
  idxcopy_kernel<<<(2 * ECNT + 255) / 256, 256, 0, stream>>>(ei, out + (size_t)NF * OUTD);
}